// Round 5
// baseline (2484.751 us; speedup 1.0000x reference)
//
#include <hip/hip_runtime.h>
#include <hip/hip_bf16.h>
#include <math.h>

// EventTransformer on MI355X — round 5: swapped-QK MFMA flash attention
// (256 q/block, source-swizzled K staging, padded V^T), bf16 MFMA GEMMs.
// Packed-token layout: rows 0..N-1 = DOM tokens, rows N..N+B-1 = CLS tokens.

#define D_INPUT  128
#define DM       256
#define NHEADS   4
#define HDIM     64
#define NLAYERS  4
#define DFF      1024
#define BEV      128
#define LNEPS    1e-5f
#define GRIDY    3

typedef unsigned short u16;
typedef __attribute__((ext_vector_type(8))) short bf16x8;
typedef __attribute__((ext_vector_type(4))) float f32x4;

__device__ inline float bf2f(u16 u) {
    union { unsigned int i; float f; } c; c.i = ((unsigned int)u) << 16; return c.f;
}
__device__ inline u16 f2bf(float x) {
    unsigned int xi = __float_as_uint(x);
    unsigned int r  = xi + 0x7FFFu + ((xi >> 16) & 1u);   // RNE
    return (u16)(r >> 16);
}

// async global->LDS, 16B per lane; LDS dest = wave-uniform base + lane*16
__device__ inline void gload16(const void* g, void* l) {
    __builtin_amdgcn_global_load_lds(
        (const __attribute__((address_space(1))) unsigned int*)g,
        (__attribute__((address_space(3))) unsigned int*)l, 16, 0, 0);
}

// V^T LDS index: [d][k], stride 72 + 8-u16 pad per 16 d-rows (bank spread)
__device__ inline int vt_idx(int d, int k) { return d * 72 + (d >> 4) * 8 + k; }

// ---------------- prep kernels ----------------

__global__ void zero_counts_kernel(int* counts) { counts[threadIdx.x] = 0; }

__global__ void count_kernel(const int* __restrict__ idx, int* __restrict__ counts, int N) {
    int i = blockIdx.x * blockDim.x + threadIdx.x;
    if (i < N) atomicAdd(&counts[idx[i]], 1);
}

__global__ void scan_kernel(const int* __restrict__ counts, int* __restrict__ starts) {
    if (threadIdx.x == 0) {
        int s = 0;
        for (int b = 0; b < BEV; ++b) { starts[b] = s; s += counts[b]; }
    }
}

__global__ void beacon_kernel(float* out, int n, float v) {
    int i = blockIdx.x * blockDim.x + threadIdx.x;
    if (i < n) out[i] = v;
}

// merged fp32->bf16 conversion of all 4 weight groups
__global__ void cvt4_kernel(const float* __restrict__ s0, const float* __restrict__ s1,
                            const float* __restrict__ s2, const float* __restrict__ s3,
                            u16* __restrict__ d0, u16* __restrict__ d1,
                            u16* __restrict__ d2, u16* __restrict__ d3,
                            int n0, int n1, int n2, int n3) {
    int i = blockIdx.x * blockDim.x + threadIdx.x;
    if (i < n0) { d0[i] = f2bf(s0[i]); return; }
    i -= n0;
    if (i < n1) { d1[i] = f2bf(s1[i]); return; }
    i -= n1;
    if (i < n2) { d2[i] = f2bf(s2[i]); return; }
    i -= n2;
    if (i < n3) d3[i] = f2bf(s3[i]);
}

// We (256 x 384) bf16 = [in_proj_w | geo_proj_w[:, :252] | 0]; be = in_b + geo_b (f32).
__global__ void prep_w_kernel(const float* __restrict__ win, const float* __restrict__ wgeo,
                              const float* __restrict__ bin, const float* __restrict__ bgeo,
                              u16* __restrict__ We, float* __restrict__ be) {
    int i = blockIdx.x * blockDim.x + threadIdx.x;
    if (i < 256 * 384) {
        int o = i / 384, k = i % 384;
        float v = 0.f;
        if (k < 128)      v = win[o * 128 + k];
        else if (k < 380) v = wgeo[o * 256 + (k - 128)];
        We[i] = f2bf(v);
    }
    if (i < 256) be[i] = bin[i] + bgeo[i];
}

// A (N x 384) bf16 = [dom_embeddings | pos_enc (252) | 0].
__global__ void prep_a_kernel(const float* __restrict__ emb, const float* __restrict__ geo,
                              u16* __restrict__ A, int N) {
    size_t i = (size_t)blockIdx.x * blockDim.x + threadIdx.x;
    if (i >= (size_t)N * 384) return;
    int k = (int)(i % 384);
    size_t r = i / 384;
    float v = 0.f;
    if (k < 128) {
        v = emb[r * 128 + k];
    } else if (k < 380) {
        int rem  = k - 128;
        int axis = rem / 84;
        int r2   = rem % 84;
        int band = r2 >> 1;
        int sc   = r2 & 1;
        float freq = expf((float)band * (2.3025850929940457f / 41.0f)); // 10^(band/41)
        float ang  = (6.283185307179586f * geo[r * 3 + axis]) * freq;
        v = sc ? cosf(ang) : sinf(ang);
    }
    A[i] = f2bf(v);
}

__global__ void cls_kernel(const float* __restrict__ cls, float* __restrict__ h, int N) {
    h[(size_t)(N + blockIdx.x) * DM + threadIdx.x] = cls[threadIdx.x];
}

// ---------------- layernorm: fp32 in, bf16 out; one wave per row ----------------

__global__ __launch_bounds__(256) void ln_kernel(const float* __restrict__ x,
                                                 const float* __restrict__ w,
                                                 const float* __restrict__ b,
                                                 u16* __restrict__ y, int T) {
    int row  = blockIdx.x * 4 + (threadIdx.x >> 6);
    int lane = threadIdx.x & 63;
    if (row >= T) return;
    float4 v = ((const float4*)(x + (size_t)row * DM))[lane];
    float s = v.x + v.y + v.z + v.w;
    #pragma unroll
    for (int off = 32; off > 0; off >>= 1) s += __shfl_xor(s, off);
    float mean = s * (1.0f / 256.0f);
    float dx = v.x - mean, dy = v.y - mean, dz = v.z - mean, dw = v.w - mean;
    float ss = dx * dx + dy * dy + dz * dz + dw * dw;
    #pragma unroll
    for (int off = 32; off > 0; off >>= 1) ss += __shfl_xor(ss, off);
    float inv = rsqrtf(ss * (1.0f / 256.0f) + LNEPS);
    float4 wv = ((const float4*)w)[lane];
    float4 bv = ((const float4*)b)[lane];
    ushort4 o;
    o.x = f2bf(dx * inv * wv.x + bv.x);
    o.y = f2bf(dy * inv * wv.y + bv.y);
    o.z = f2bf(dz * inv * wv.z + bv.z);
    o.w = f2bf(dw * inv * wv.w + bv.w);
    ((ushort4*)(y + (size_t)row * DM))[lane] = o;
}

// ---------------- bf16 MFMA GEMM (m97 structure, validated) ----------------

template <typename OutT>
__global__ __launch_bounds__(256) void mgemm_kernel(const u16* __restrict__ A,
                                                    const u16* __restrict__ W,
                                                    const float* __restrict__ bias,
                                                    OutT* __restrict__ C,
                                                    int K, int No, int flags) {
    __shared__ u16 As[128 * 64];
    __shared__ u16 Bs[128 * 64];
    const int m0 = blockIdx.y * 128, n0 = blockIdx.x * 128;
    const int tid  = threadIdx.x;
    const int w    = tid >> 6, lane = tid & 63;
    const int wr   = w >> 1,  wc   = w & 1;
    const int lhi  = lane >> 4, llo = lane & 15;

    f32x4 acc[4][4];
    #pragma unroll
    for (int i = 0; i < 4; ++i)
        #pragma unroll
        for (int j = 0; j < 4; ++j) acc[i][j] = (f32x4){0.f, 0.f, 0.f, 0.f};

    for (int kt = 0; kt < K; kt += 64) {
        __syncthreads();
        #pragma unroll
        for (int it = 0; it < 4; ++it) {
            int un = it * 256 + tid;
            int r = un >> 3, c8 = un & 7;
            gload16(A + (size_t)(m0 + r) * K + kt + c8 * 8, &As[un * 8]);
            gload16(W + (size_t)(n0 + r) * K + kt + c8 * 8, &Bs[un * 8]);
        }
        __syncthreads();
        #pragma unroll
        for (int kk = 0; kk < 2; ++kk) {
            bf16x8 af[4], bfr[4];
            #pragma unroll
            for (int i = 0; i < 4; ++i)
                af[i] = *(const bf16x8*)&As[(wr * 64 + i * 16 + llo) * 64 + kk * 32 + lhi * 8];
            #pragma unroll
            for (int j = 0; j < 4; ++j)
                bfr[j] = *(const bf16x8*)&Bs[(wc * 64 + j * 16 + llo) * 64 + kk * 32 + lhi * 8];
            #pragma unroll
            for (int i = 0; i < 4; ++i)
                #pragma unroll
                for (int j = 0; j < 4; ++j)
                    acc[i][j] = __builtin_amdgcn_mfma_f32_16x16x32_bf16(af[i], bfr[j], acc[i][j], 0, 0, 0);
        }
    }

    #pragma unroll
    for (int i = 0; i < 4; ++i) {
        #pragma unroll
        for (int j = 0; j < 4; ++j) {
            const int row0 = m0 + wr * 64 + i * 16 + lhi * 4;
            const int col  = n0 + wc * 64 + j * 16 + llo;
            const float bb = bias[col];
            #pragma unroll
            for (int r = 0; r < 4; ++r) {
                float v = acc[i][j][r] + bb;
                size_t idx = (size_t)(row0 + r) * No + col;
                if constexpr (sizeof(OutT) == 4) {
                    float* cp = (float*)C + idx;
                    if (flags & 2) v += *cp;
                    if (flags & 1) v = fmaxf(v, 0.f);
                    *cp = v;
                } else {
                    if (flags & 1) v = fmaxf(v, 0.f);
                    ((u16*)C)[idx] = f2bf(v);
                }
            }
        }
    }
}

// ---------------- swapped-QK MFMA flash attention ----------------
// Block = (event b, head h); 4 waves x 64 q-rows = 256 q/block; KV tiles of 64.
// QK^T computed as mfma(A=K, B=Q) -> S^T[k][q]: lane(llo,lhi) holds q=llo,
// keys i*16+lhi*4+r -> row softmax is in-register + 2 shfl.
// PV as mfma(A=V^T, B=P) -> O^T[d][q]. All layouts follow the m89-verified
// convention used in mgemm.

__global__ __launch_bounds__(256) void mattn_kernel(const u16* __restrict__ qkv,
                                                    const int* __restrict__ counts,
                                                    const int* __restrict__ starts,
                                                    u16* __restrict__ out, int N) {
    const int b  = blockIdx.x >> 2;
    const int hh = blockIdx.x & 3;
    const int Sb = counts[b] + 1;
    const int start = starts[b];
    __shared__ u16 Ks[64 * 64];       // [k][d], chunk-swizzled (c ^= k&7)
    __shared__ u16 Vt[4624];          // [d][k], padded stride
    __shared__ u16 Pl[4][16 * 72];    // per-wave P (16q x 64k)
    const int tid = threadIdx.x;
    const int w = tid >> 6, lane = tid & 63;
    const int llo = lane & 15, lhi = lane >> 4;
    const int sr = tid >> 2, sseg = tid & 3;

    for (int qb0 = blockIdx.y * 256; qb0 < Sb; qb0 += GRIDY * 256) {
        const int qw = qb0 + w * 64;
        const bool wactive = qw < Sb;

        bf16x8 bq[4][2];
        if (wactive) {
            #pragma unroll
            for (int qf = 0; qf < 4; ++qf) {
                const int qi = qw + qf * 16 + llo;
                const size_t qrow = (qi < Sb && qi > 0) ? (size_t)(start + qi - 1) : (size_t)(N + b);
                #pragma unroll
                for (int kk = 0; kk < 2; ++kk)
                    bq[qf][kk] = *(const bf16x8*)(qkv + qrow * 768 + hh * 64 + kk * 32 + lhi * 8);
            }
        }
        f32x4 acc[4][4];   // [d-tile][qf]
        #pragma unroll
        for (int i = 0; i < 4; ++i)
            #pragma unroll
            for (int qf = 0; qf < 4; ++qf) acc[i][qf] = (f32x4){0.f, 0.f, 0.f, 0.f};
        float m[4] = {-1e30f, -1e30f, -1e30f, -1e30f};
        float l[4] = {0.f, 0.f, 0.f, 0.f};

        for (int kbase = 0; kbase < Sb; kbase += 64) {
            __syncthreads();   // previous tile's LDS reads complete
            // stage K: async global->LDS, source chunk pre-swizzled
            #pragma unroll
            for (int it = 0; it < 2; ++it) {
                const int u = it * 256 + tid;
                const int r = u >> 3, c = u & 7;
                const int ki = kbase + r;
                if (ki < Sb) {
                    const size_t krow = (ki == 0) ? (size_t)(N + b) : (size_t)(start + ki - 1);
                    gload16(qkv + krow * 768 + 256 + hh * 64 + ((c ^ (r & 7)) * 8), &Ks[u * 8]);
                }
            }
            // stage V: regs -> transposed scatter (invalid rows zeroed)
            {
                const int ki = kbase + sr;
                uint4 v0 = {0, 0, 0, 0}, v1 = {0, 0, 0, 0};
                if (ki < Sb) {
                    const size_t krow = (ki == 0) ? (size_t)(N + b) : (size_t)(start + ki - 1);
                    const u16* vp = qkv + krow * 768 + 512 + hh * 64 + sseg * 16;
                    v0 = *(const uint4*)vp;
                    v1 = *(const uint4*)(vp + 8);
                }
                u16 vv[16];
                *(uint4*)&vv[0] = v0;
                *(uint4*)&vv[8] = v1;
                #pragma unroll
                for (int u = 0; u < 16; ++u) {
                    const int d = sseg * 16 + u;
                    Vt[vt_idx(d, sr)] = vv[u];
                }
            }
            __syncthreads();

            if (wactive) {
                bf16x8 ak[4][2], av[4][2];
                #pragma unroll
                for (int i = 0; i < 4; ++i) {
                    const int kr = i * 16 + llo;
                    #pragma unroll
                    for (int kk = 0; kk < 2; ++kk)
                        ak[i][kk] = *(const bf16x8*)&Ks[kr * 64 + (((kk * 4 + lhi) ^ (kr & 7)) * 8)];
                    const int d = i * 16 + llo;
                    #pragma unroll
                    for (int kk2 = 0; kk2 < 2; ++kk2)
                        av[i][kk2] = *(const bf16x8*)&Vt[vt_idx(d, kk2 * 32 + lhi * 8)];
                }
                #pragma unroll
                for (int qf = 0; qf < 4; ++qf) {
                    f32x4 sc[4];
                    #pragma unroll
                    for (int i = 0; i < 4; ++i) sc[i] = (f32x4){0.f, 0.f, 0.f, 0.f};
                    #pragma unroll
                    for (int kk = 0; kk < 2; ++kk)
                        #pragma unroll
                        for (int i = 0; i < 4; ++i)
                            sc[i] = __builtin_amdgcn_mfma_f32_16x16x32_bf16(ak[i][kk], bq[qf][kk], sc[i], 0, 0, 0);

                    // scale + mask; lane holds 16 scores for q = qf*16+llo
                    float sj[4][4];
                    float rm = -1e30f;
                    #pragma unroll
                    for (int i = 0; i < 4; ++i) {
                        #pragma unroll
                        for (int r = 0; r < 4; ++r) {
                            const int key = kbase + i * 16 + lhi * 4 + r;
                            const float s = (key < Sb) ? sc[i][r] * 0.125f : -1e30f;
                            sj[i][r] = s;
                            rm = fmaxf(rm, s);
                        }
                    }
                    rm = fmaxf(rm, __shfl_xor(rm, 16));
                    rm = fmaxf(rm, __shfl_xor(rm, 32));

                    const float mnew = fmaxf(m[qf], rm);
                    const float corr = __expf(m[qf] - mnew);
                    m[qf] = mnew;
                    float ls = 0.f;
                    ushort4 pw[4];
                    #pragma unroll
                    for (int i = 0; i < 4; ++i) {
                        float p0 = __expf(sj[i][0] - mnew), p1 = __expf(sj[i][1] - mnew);
                        float p2 = __expf(sj[i][2] - mnew), p3 = __expf(sj[i][3] - mnew);
                        ls += (p0 + p1) + (p2 + p3);
                        pw[i].x = f2bf(p0); pw[i].y = f2bf(p1);
                        pw[i].z = f2bf(p2); pw[i].w = f2bf(p3);
                    }
                    ls += __shfl_xor(ls, 16);
                    ls += __shfl_xor(ls, 32);
                    l[qf] = l[qf] * corr + ls;
                    #pragma unroll
                    for (int i = 0; i < 4; ++i) acc[i][qf] *= corr;

                    // P -> per-wave LDS (vectorized), read back as B-frags
                    #pragma unroll
                    for (int i = 0; i < 4; ++i)
                        *(ushort4*)&Pl[w][llo * 72 + i * 16 + lhi * 4] = pw[i];
                    #pragma unroll
                    for (int kk2 = 0; kk2 < 2; ++kk2) {
                        bf16x8 pb = *(const bf16x8*)&Pl[w][llo * 72 + kk2 * 32 + lhi * 8];
                        #pragma unroll
                        for (int i = 0; i < 4; ++i)
                            acc[i][qf] = __builtin_amdgcn_mfma_f32_16x16x32_bf16(av[i][kk2], pb, acc[i][qf], 0, 0, 0);
                    }
                }
            }
        }

        if (wactive) {
            #pragma unroll
            for (int qf = 0; qf < 4; ++qf) {
                const int qi = qw + qf * 16 + llo;
                if (qi < Sb) {
                    const size_t orow = (qi == 0) ? (size_t)(N + b) : (size_t)(start + qi - 1);
                    const float invl = 1.f / l[qf];
                    #pragma unroll
                    for (int i = 0; i < 4; ++i) {
                        ushort4 o;
                        o.x = f2bf(acc[i][qf][0] * invl);
                        o.y = f2bf(acc[i][qf][1] * invl);
                        o.z = f2bf(acc[i][qf][2] * invl);
                        o.w = f2bf(acc[i][qf][3] * invl);
                        *(ushort4*)&out[orow * DM + hh * HDIM + i * 16 + lhi * 4] = o;
                    }
                }
            }
        }
    }
}

// ---------------- head ----------------

__global__ __launch_bounds__(256) void head_kernel(const float* __restrict__ h,
                                                   const float* __restrict__ w1,
                                                   const float* __restrict__ b1,
                                                   const float* __restrict__ w2,
                                                   const float* __restrict__ b2,
                                                   float* __restrict__ out, int N) {
    const int b = blockIdx.x;
    const int t = threadIdx.x;
    __shared__ float cls[DM];
    __shared__ float hid[DM];
    cls[t] = h[(size_t)(N + b) * DM + t];
    __syncthreads();
    float s = b1[t];
    for (int k = 0; k < DM; ++k) s = fmaf(cls[k], w1[t * DM + k], s);
    hid[t] = fmaxf(s, 0.f);
    __syncthreads();
    if (t < 2) {
        float o = b2[t];
        for (int k = 0; k < DM; ++k) o = fmaf(hid[k], w2[t * DM + k], o);
        out[b * 2 + t] = o;
    }
}

// ---------------- launch ----------------

extern "C" void kernel_launch(void* const* d_in, const int* in_sizes, int n_in,
                              void* d_out, int out_size, void* d_ws, size_t ws_size,
                              hipStream_t stream) {
    const float* dom_emb   = (const float*)d_in[0];
    const int*   dom_idx   = (const int*)d_in[1];
    const float* geometry  = (const float*)d_in[3];
    const float* in_w      = (const float*)d_in[4];
    const float* in_b      = (const float*)d_in[5];
    const float* geo_w     = (const float*)d_in[6];
    const float* geo_b     = (const float*)d_in[7];
    const float* cls_tok   = (const float*)d_in[8];
    const float* qkv_w     = (const float*)d_in[9];
    const float* qkv_b     = (const float*)d_in[10];
    const float* out_w     = (const float*)d_in[11];
    const float* out_b     = (const float*)d_in[12];
    const float* ln1_w     = (const float*)d_in[13];
    const float* ln1_b     = (const float*)d_in[14];
    const float* ln2_w     = (const float*)d_in[15];
    const float* ln2_b     = (const float*)d_in[16];
    const float* ff_w1     = (const float*)d_in[17];
    const float* ff_b1     = (const float*)d_in[18];
    const float* ff_w2     = (const float*)d_in[19];
    const float* ff_b2     = (const float*)d_in[20];
    const float* head_w1   = (const float*)d_in[21];
    const float* head_b1   = (const float*)d_in[22];
    const float* head_w2   = (const float*)d_in[23];
    const float* head_b2   = (const float*)d_in[24];
    float* outp = (float*)d_out;

    const int N = in_sizes[0] / D_INPUT;       // 65536
    const int T = N + BEV;                     // 65664 = 513 * 128

    // workspace layout (bytes). Total ~208.3 MB.
    char* base = (char*)d_ws;
    size_t off = 0;
    int* counts = (int*)(base + off);          off += 1024;
    int* starts = (int*)(base + off);          off += 1024;
    u16*   Web  = (u16*)(base + off);          off += (size_t)256 * 384 * 2;
    float* be   = (float*)(base + off);        off += 1024;
    u16*   wq   = (u16*)(base + off);          off += (size_t)NLAYERS * 768 * 256 * 2;
    u16*   wo   = (u16*)(base + off);          off += (size_t)NLAYERS * 256 * 256 * 2;
    u16*   w1b  = (u16*)(base + off);          off += (size_t)NLAYERS * 1024 * 256 * 2;
    u16*   w2b  = (u16*)(base + off);          off += (size_t)NLAYERS * 256 * 1024 * 2;
    float* h    = (float*)(base + off);        off += (size_t)T * DM * 4;     // 67.2 MB
    u16*   xb   = (u16*)(base + off);          off += (size_t)T * DM * 2;     // 33.6 MB
    char*  bigc = base + off;                  off += (size_t)T * 768 * 2;    // 100.9 MB
    u16* Ab   = (u16*)bigc;     // embed A (N x 384 bf16)
    u16* qkvb = (u16*)bigc;     // qkv (T x 768 bf16)
    u16* ffm  = (u16*)bigc;     // FF mid chunk (<=32896 x 1024 bf16 = 67.4 MB)

    if (ws_size < off) {
        beacon_kernel<<<1, 256, 0, stream>>>(outp, out_size, (float)(ws_size >> 20));
        return;
    }

    // ---- weight conversion to bf16 (single kernel) ----
    {
        const int n0 = NLAYERS * 768 * 256, n1 = NLAYERS * 256 * 256;
        const int n2 = NLAYERS * 1024 * 256, n3 = NLAYERS * 256 * 1024;
        cvt4_kernel<<<(n0 + n1 + n2 + n3 + 255) / 256, 256, 0, stream>>>(
            qkv_w, out_w, ff_w1, ff_w2, wq, wo, w1b, w2b, n0, n1, n2, n3);
    }
    prep_w_kernel<<<(256 * 384 + 255) / 256, 256, 0, stream>>>(in_w, geo_w, in_b, geo_b, Web, be);

    // ---- event bookkeeping ----
    zero_counts_kernel<<<1, BEV, 0, stream>>>(counts);
    count_kernel<<<(N + 255) / 256, 256, 0, stream>>>(dom_idx, counts, N);
    scan_kernel<<<1, 64, 0, stream>>>(counts, starts);

    // ---- embed ----
    prep_a_kernel<<<(int)(((size_t)N * 384 + 255) / 256), 256, 0, stream>>>(dom_emb, geometry, Ab, N);
    mgemm_kernel<float><<<dim3(2, N / 128), 256, 0, stream>>>(Ab, Web, be, h, 384, DM, 0);
    cls_kernel<<<BEV, DM, 0, stream>>>(cls_tok, h, N);

    // ---- transformer layers ----
    const int lnGrid = (T + 3) / 4;
    const int TILES = T / 128;                 // 513
    const int CH1 = 257, CH2 = TILES - CH1;    // FF row-tile chunks
    for (int l = 0; l < NLAYERS; ++l) {
        ln_kernel<<<lnGrid, 256, 0, stream>>>(h, ln1_w + l * DM, ln1_b + l * DM, xb, T);
        mgemm_kernel<u16><<<dim3(6, TILES), 256, 0, stream>>>(
            xb, wq + (size_t)l * 768 * 256, qkv_b + l * 768, qkvb, 256, 768, 0);
        mattn_kernel<<<dim3(BEV * NHEADS, GRIDY), 256, 0, stream>>>(qkvb, counts, starts, xb, N);
        mgemm_kernel<float><<<dim3(2, TILES), 256, 0, stream>>>(
            xb, wo + (size_t)l * 256 * 256, out_b + l * DM, h, 256, DM, 2);
        ln_kernel<<<lnGrid, 256, 0, stream>>>(h, ln2_w + l * DM, ln2_b + l * DM, xb, T);
        const int chs[2] = {CH1, CH2};
        int t0 = 0;
        for (int c = 0; c < 2; ++c) {
            const size_t r0 = (size_t)t0 * 128;
            mgemm_kernel<u16><<<dim3(8, chs[c]), 256, 0, stream>>>(
                xb + r0 * DM, w1b + (size_t)l * DFF * 256, ff_b1 + l * DFF, ffm, 256, DFF, 1);
            mgemm_kernel<float><<<dim3(2, chs[c]), 256, 0, stream>>>(
                ffm, w2b + (size_t)l * 256 * DFF, ff_b2 + l * DM, h + r0 * DM, DFF, DM, 2);
            t0 += chs[c];
        }
    }

    // ---- head ----
    head_kernel<<<BEV, DM, 0, stream>>>(h, head_w1, head_b1, head_w2, head_b2, outp, N);
}